// Round 1
// 898.201 us; speedup vs baseline: 1.0992x; 1.0992x over previous
//
#include <hip/hip_runtime.h>
#include <hip/hip_bf16.h>

#define NB   256
#define NT   32
#define NV   10000
#define NVP  10240
#define NDF  1280
#define NH   512
#define VT_N 40      // vocab col tiles of 256

typedef short bf16x8 __attribute__((ext_vector_type(8)));
typedef float f32x4  __attribute__((ext_vector_type(4)));
typedef unsigned short u16;

__device__ __forceinline__ float b2f(u16 u) {
    union { unsigned i; float f; } v; v.i = ((unsigned)u) << 16; return v.f;
}
__device__ __forceinline__ u16 f2b(float f) {
    union { float f; unsigned i; } v; v.f = f;
    unsigned r = v.i + 0x7FFF + ((v.i >> 16) & 1);   // RNE
    return (u16)(r >> 16);
}

// async global->LDS, 16B per lane; lds dest must be wave-uniform base
__device__ __forceinline__ void gload16(const u16* g, u16* l) {
    __builtin_amdgcn_global_load_lds(
        (const __attribute__((address_space(1))) void*)g,
        (__attribute__((address_space(3))) void*)l, 16, 0, 0);
}

// ---------------- workspace layout (byte offsets, 16-aligned) --------------
static const size_t B_C     = 0;                                  // [256][512] f32 cell
static const size_t B_SCP   = B_C     + (size_t)256*512*4;        // [2][32][256][16] f32
static const size_t B_PMAX  = B_SCP   + (size_t)2*32*256*16*4;    // [8192][40] f32
static const size_t B_PSUM  = B_PMAX  + (size_t)8192*VT_N*4;      // [8192][40] f32
static const size_t B_TGT   = B_PSUM  + (size_t)8192*VT_N*4;      // [8192] f32
static const size_t B_LOSS  = B_TGT   + (size_t)8192*4;           // [1] f32
static const size_t B_AB    = B_LOSS  + 16;                       // [256][16][512] bf16
static const size_t B_XPB   = B_AB    + (size_t)256*16*512*2;     // [32][256][2048] bf16
static const size_t B_HALLB = B_XPB   + (size_t)32*256*2048*2;    // [32][256][512] bf16
static const size_t B_WVT   = B_HALLB + (size_t)32*256*512*2;     // [10240][512] bf16
static const size_t B_WXT   = B_WVT   + (size_t)10240*512*2;      // [2048][256] bf16
static const size_t B_WHAT  = B_WXT   + (size_t)2048*256*2;       // [2048][1024] bf16
static const size_t B_HB0   = B_WHAT  + (size_t)2048*1024*2;      // [256][512] bf16 h ping
static const size_t B_HB1   = B_HB0   + (size_t)256*512*2;        // [256][512] bf16 h pong
static const size_t B_PREAW = B_HB1   + (size_t)256*512*2;        // [16*256][2048] bf16
// Aliases (prep-only, dead before overwriter runs):
//   fT  (4096x1280 bf16 = 10.49 MB) lives at B_WVT  (wvt written later)
//   WpT (512x1280 bf16 = 1.31 MB)   lives at B_XPB  (xpb written later)

// ---------------------------------------------------------------------------
// T0: transpose+convert: src f32 [K][N] -> dst bf16 [Npad][ldK] at koff.
__global__ __launch_bounds__(256) void tconv_kernel(
    const float* __restrict__ src, u16* __restrict__ dst,
    int K, int N, int Npad, int ldK, int koff)
{
    __shared__ u16 tile[64][65];
    const int k0 = blockIdx.y * 64, n0 = blockIdx.x * 64, tid = threadIdx.x;
#pragma unroll
    for (int i = 0; i < 16; i++) {
        int idx = tid + i * 256;
        int kk = idx >> 6, nn = idx & 63;
        int n = n0 + nn;
        float v = (n < N) ? src[(size_t)(k0 + kk) * N + n] : 0.f;
        tile[kk][nn] = f2b(v);
    }
    __syncthreads();
#pragma unroll
    for (int i = 0; i < 16; i++) {
        int idx = tid + i * 256;
        int nn = idx >> 6, kk = idx & 63;
        int n = n0 + nn;
        if (n < Npad) dst[(size_t)n * ldK + koff + k0 + kk] = tile[kk][nn];
    }
}

// ---------------------------------------------------------------------------
// P1: feats f32 [n][c][p16] -> fT bf16 [n*16+p][1280]. grid (20 cch, 256 n).
__global__ __launch_bounds__(256) void ftrans_kernel(
    const float* __restrict__ feats, u16* __restrict__ fT)
{
    const int cch = blockIdx.x, n = blockIdx.y, tid = threadIdx.x;
    __shared__ u16 lt[64][17];
    const int c0 = cch * 64;
    const int c = tid >> 2, p4 = (tid & 3) * 4;
    float4 v = *(const float4*)(feats + (size_t)n * 20480 + (size_t)(c0 + c) * 16 + p4);
    lt[c][p4] = f2b(v.x); lt[c][p4 + 1] = f2b(v.y);
    lt[c][p4 + 2] = f2b(v.z); lt[c][p4 + 3] = f2b(v.w);
    __syncthreads();
    const int p = tid >> 4, cg = tid & 15;
    ushort4 o;
    o.x = lt[cg * 4 + 0][p]; o.y = lt[cg * 4 + 1][p];
    o.z = lt[cg * 4 + 2][p]; o.w = lt[cg * 4 + 3][p];
    *(ushort4*)(fT + (size_t)(n * 16 + p) * 1280 + c0 + cg * 4) = o;
}

// ---------------------------------------------------------------------------
// P2 (MFMA): Ab[row][col] = fT[row] @ WpT^T + bp, row = n*16+p. grid 64 rt.
__global__ __launch_bounds__(256) void proj_gemm_kernel(
    const u16* __restrict__ fT, const u16* __restrict__ WpT,
    const float* __restrict__ bp, u16* __restrict__ Ab)
{
    const int rt = blockIdx.x;
    const int tid = threadIdx.x, w = tid >> 6, lane = tid & 63;
    const int r0 = rt * 64;
    const int lm = lane & 15, lkq = lane >> 4, lk = lkq * 8;
    const int nbase = w * 128;

    f32x4 acc[4][8];
#pragma unroll
    for (int mt = 0; mt < 4; mt++)
#pragma unroll
        for (int nt = 0; nt < 8; nt++) acc[mt][nt] = (f32x4){0.f, 0.f, 0.f, 0.f};

    for (int kc = 0; kc < 1280; kc += 32) {
        bf16x8 af[4];
#pragma unroll
        for (int mt = 0; mt < 4; mt++)
            af[mt] = *(const bf16x8*)(fT + (size_t)(r0 + mt * 16 + lm) * 1280 + kc + lk);
#pragma unroll
        for (int nt = 0; nt < 8; nt++) {
            bf16x8 bfg = *(const bf16x8*)(WpT + (size_t)(nbase + nt * 16 + lm) * 1280 + kc + lk);
#pragma unroll
            for (int mt = 0; mt < 4; mt++)
                acc[mt][nt] = __builtin_amdgcn_mfma_f32_16x16x32_bf16(af[mt], bfg, acc[mt][nt], 0, 0, 0);
        }
    }
    float bbv[8];
#pragma unroll
    for (int nt = 0; nt < 8; nt++) bbv[nt] = bp[nbase + nt * 16 + lm];
#pragma unroll
    for (int mt = 0; mt < 4; mt++)
#pragma unroll
        for (int nt = 0; nt < 8; nt++)
#pragma unroll
            for (int r = 0; r < 4; r++) {
                int row = r0 + mt * 16 + lkq * 4 + r;
                int col = nbase + nt * 16 + lm;
                Ab[(size_t)row * 512 + col] = f2b(acc[mt][nt][r] + bbv[nt]);
            }
}

// ---------------------------------------------------------------------------
// P3: c0 = h0 = mean_p Ab (f32); hb0 = bf16(h0). grid 256.
__global__ __launch_bounds__(256) void projmean_kernel(
    const u16* __restrict__ Ab, float* __restrict__ c0, u16* __restrict__ hb0)
{
    const int n = blockIdx.x, tid = threadIdx.x;
    const int col0 = tid, col1 = tid + 256;
    float s0 = 0.f, s1 = 0.f;
#pragma unroll
    for (int p = 0; p < 16; p++) {
        const u16* ap = Ab + ((size_t)n * 16 + p) * 512;
        s0 += b2f(ap[col0]);
        s1 += b2f(ap[col1]);
    }
    s0 *= 0.0625f; s1 *= 0.0625f;
    c0[n * 512 + col0] = s0;  c0[n * 512 + col1] = s1;
    hb0[(size_t)n * 512 + col0] = f2b(s0);
    hb0[(size_t)n * 512 + col1] = f2b(s1);
}

// ---------------------------------------------------------------------------
// K2 (MFMA): xpb = embed@Wx + b  (bf16), rows stored as [t][n]
__global__ __launch_bounds__(256) void xp_mfma_kernel(
    const int* __restrict__ caps, const float* __restrict__ We,
    const u16* __restrict__ Wxt, const float* __restrict__ bb,
    u16* __restrict__ xpb)
{
    const int ct = blockIdx.x, rt = blockIdx.y;
    const int tid = threadIdx.x, w = tid >> 6, lane = tid & 63;
    const int r0 = rt * 64;
    const int lm = lane & 15, lkq = lane >> 4, lk = lkq * 8;
    const int nbase = ct * 512 + w * 128;

    int capm[4];
#pragma unroll
    for (int mt = 0; mt < 4; mt++) {
        int row = r0 + mt * 16 + lm;
        capm[mt] = caps[(row >> 5) * 33 + (row & 31)];
    }
    f32x4 acc[4][8];
#pragma unroll
    for (int mt = 0; mt < 4; mt++)
#pragma unroll
        for (int nt = 0; nt < 8; nt++) acc[mt][nt] = (f32x4){0.f, 0.f, 0.f, 0.f};

    for (int kc = 0; kc < 256; kc += 32) {
        bf16x8 af[4];
#pragma unroll
        for (int mt = 0; mt < 4; mt++) {
            const float* ap = We + (size_t)capm[mt] * 256 + kc + lk;
            float4 f0 = *(const float4*)ap;
            float4 f1 = *(const float4*)(ap + 4);
            bf16x8 t;
            t[0] = (short)f2b(f0.x); t[1] = (short)f2b(f0.y);
            t[2] = (short)f2b(f0.z); t[3] = (short)f2b(f0.w);
            t[4] = (short)f2b(f1.x); t[5] = (short)f2b(f1.y);
            t[6] = (short)f2b(f1.z); t[7] = (short)f2b(f1.w);
            af[mt] = t;
        }
#pragma unroll
        for (int nt = 0; nt < 8; nt++) {
            bf16x8 bfg = *(const bf16x8*)(Wxt + (size_t)(nbase + nt * 16 + lm) * 256 + kc + lk);
#pragma unroll
            for (int mt = 0; mt < 4; mt++)
                acc[mt][nt] = __builtin_amdgcn_mfma_f32_16x16x32_bf16(af[mt], bfg, acc[mt][nt], 0, 0, 0);
        }
    }
    float bbv[8];
#pragma unroll
    for (int nt = 0; nt < 8; nt++) bbv[nt] = bb[nbase + nt * 16 + lm];
#pragma unroll
    for (int mt = 0; mt < 4; mt++)
#pragma unroll
        for (int nt = 0; nt < 8; nt++)
#pragma unroll
            for (int r = 0; r < 4; r++) {
                int row = r0 + mt * 16 + lkq * 4 + r;   // row = n*32 + t
                int col = nbase + nt * 16 + lm;
                float v = acc[mt][nt][r] + bbv[nt];
                xpb[((size_t)(row & 31) * 256 + (row >> 5)) * 2048 + col] = f2b(v);
            }
}

// ---------------------------------------------------------------------------
// K3 (MFMA, once): PreAW[p*256+n][col] = A[n,p,:] @ Wattn  (bf16 out)
__global__ __launch_bounds__(256) void preaw_mfma_kernel(
    const u16* __restrict__ Ab, const u16* __restrict__ what,
    u16* __restrict__ preaw)
{
    const int ct = blockIdx.x, rt = blockIdx.y;
    const int tid = threadIdx.x, w = tid >> 6, lane = tid & 63;
    const int r0 = rt * 64;
    const int lm = lane & 15, lkq = lane >> 4, lk = lkq * 8;
    const int nbase = ct * 512 + w * 128;

    f32x4 acc[4][8];
#pragma unroll
    for (int mt = 0; mt < 4; mt++)
#pragma unroll
        for (int nt = 0; nt < 8; nt++) acc[mt][nt] = (f32x4){0.f, 0.f, 0.f, 0.f};

    for (int kc = 0; kc < 512; kc += 32) {
        bf16x8 af[4];
#pragma unroll
        for (int mt = 0; mt < 4; mt++) {
            int row = r0 + mt * 16 + lm;                  // row = p*256+n
            af[mt] = *(const bf16x8*)(Ab + ((size_t)(row & 255) * 16 + (row >> 8)) * 512 + kc + lk);
        }
#pragma unroll
        for (int nt = 0; nt < 8; nt++) {
            bf16x8 bfg = *(const bf16x8*)(what + (size_t)(nbase + nt * 16 + lm) * 1024 + 512 + kc + lk);
#pragma unroll
            for (int mt = 0; mt < 4; mt++)
                acc[mt][nt] = __builtin_amdgcn_mfma_f32_16x16x32_bf16(af[mt], bfg, acc[mt][nt], 0, 0, 0);
        }
    }
#pragma unroll
    for (int mt = 0; mt < 4; mt++)
#pragma unroll
        for (int nt = 0; nt < 8; nt++)
#pragma unroll
            for (int r = 0; r < 4; r++) {
                int row = r0 + mt * 16 + lkq * 4 + r;
                int col = nbase + nt * 16 + lm;
                preaw[(size_t)row * 2048 + col] = f2b(acc[mt][nt][r]);
            }
}

// ---------------------------------------------------------------------------
// K4 (once): scores for t=0: scp[0][n][p] = h0[n]·A[n,p]; zero cg>0
__global__ __launch_bounds__(64) void score_init_kernel(
    const u16* __restrict__ hb0, const u16* __restrict__ Ab,
    float* __restrict__ scp)
{
    const int n = blockIdx.x, lane = threadIdx.x;
    const u16* hp = hb0 + (size_t)n * 512 + lane * 8;
    ushort4 h0 = *(const ushort4*)hp, h1 = *(const ushort4*)(hp + 4);
    float hv0 = b2f(h0.x), hv1 = b2f(h0.y), hv2 = b2f(h0.z), hv3 = b2f(h0.w);
    float hv4 = b2f(h1.x), hv5 = b2f(h1.y), hv6 = b2f(h1.z), hv7 = b2f(h1.w);
    float mine = 0.f;
#pragma unroll
    for (int p = 0; p < 16; p++) {
        const u16* ap = Ab + (size_t)n * 8192 + p * 512 + lane * 8;
        ushort4 a0 = *(const ushort4*)ap, a1 = *(const ushort4*)(ap + 4);
        float s = hv0*b2f(a0.x) + hv1*b2f(a0.y) + hv2*b2f(a0.z) + hv3*b2f(a0.w)
                + hv4*b2f(a1.x) + hv5*b2f(a1.y) + hv6*b2f(a1.z) + hv7*b2f(a1.w);
#pragma unroll
        for (int mask = 1; mask <= 32; mask <<= 1) s += __shfl_xor(s, mask, 64);
        if (lane == p) mine = s;
    }
    if (lane < 16) scp[n * 16 + lane] = mine;
    for (int i = lane; i < 31 * 16; i += 64)
        scp[(1 + (i >> 4)) * 4096 + n * 16 + (i & 15)] = 0.f;
}

// ---------------------------------------------------------------------------
// K5 (per step): softmax(scores) -> gates MFMA + PreAW attn + nonlin ->
// c,h update -> score partials for t+1. grid (16 rt, 32 cg), 4 waves.
__global__ __launch_bounds__(256) void gates_fused_kernel(
    const u16* __restrict__ hb_in, const float* __restrict__ scp_in,
    const u16* __restrict__ what, const u16* __restrict__ preaw,
    const u16* __restrict__ xpt, const u16* __restrict__ Ab,
    float* __restrict__ c, u16* __restrict__ hb_out,
    u16* __restrict__ hallbt, float* __restrict__ scp_out)
{
    const int rt = blockIdx.x, cg = blockIdx.y;
    const int tid = threadIdx.x, ty = tid >> 6, lane = tid & 63;
    const int lm = lane & 15, lkq = lane >> 4, lk = lkq * 8;
    const int r0 = rt * 16, hc0 = cg * 16;

    __shared__ u16 hs[16 * 520];
    __shared__ float sred[16][17];
    __shared__ float wts[16][17];
    __shared__ float gred[3][64][4];
    __shared__ u16 hnew[16][16];

#pragma unroll
    for (int i = 0; i < 8; i++) {
        int fid = tid + i * 256;
        int r = fid >> 7, c4 = fid & 127;
        *(ushort4*)&hs[r * 520 + c4 * 4] =
            *(const ushort4*)(hb_in + (size_t)(r0 + r) * 512 + c4 * 4);
    }
    {
        const int r = tid >> 4, p = tid & 15;
        float s = 0.f;
#pragma unroll
        for (int g = 0; g < 32; g++) s += scp_in[g * 4096 + (r0 + r) * 16 + p];
        sred[r][p] = s * 0.04419417382415922f;
    }
    __syncthreads();
    {
        const int r = tid >> 4, p = tid & 15;
        float m = -1e30f;
#pragma unroll
        for (int q = 0; q < 16; q++) m = fmaxf(m, sred[r][q]);
        float su = 0.f;
#pragma unroll
        for (int q = 0; q < 16; q++) su += __expf(sred[r][q] - m);
        wts[r][p] = __expf(sred[r][p] - m) / su;
    }
    __syncthreads();

    f32x4 acc = (f32x4){0.f, 0.f, 0.f, 0.f};
    const u16* brow = what + (size_t)(ty * 512 + hc0 + lm) * 1024 + lk;
    const u16* arow = &hs[lm * 520 + lk];
    for (int kc = 0; kc < 512; kc += 32) {
        bf16x8 af = *(const bf16x8*)(arow + kc);
        bf16x8 bfg = *(const bf16x8*)(brow + kc);
        acc = __builtin_amdgcn_mfma_f32_16x16x32_bf16(af, bfg, acc, 0, 0, 0);
    }
    float val[4];
#pragma unroll
    for (int r = 0; r < 4; r++) {
        const int rl = lkq * 4 + r, n = r0 + rl;
        const int col = ty * 512 + hc0 + lm;
        float s = acc[r] + b2f(xpt[(size_t)n * 2048 + col]);
#pragma unroll
        for (int p = 0; p < 16; p++)
            s += wts[rl][p] * b2f(preaw[((size_t)p * 256 + n) * 2048 + col]);
        val[r] = s;
    }
    if (ty > 0) {
#pragma unroll
        for (int r = 0; r < 4; r++) gred[ty - 1][lane][r] = val[r];
    }
    __syncthreads();
    if (ty == 0) {
#pragma unroll
        for (int r = 0; r < 4; r++) {
            const int rl = lkq * 4 + r, n = r0 + rl;
            const int hcol = hc0 + lm;
            float ai  = val[r];
            float af_ = gred[0][lane][r];
            float ao  = gred[1][lane][r];
            float ag  = gred[2][lane][r];
            float ig = 1.f / (1.f + __expf(-ai));
            float fg = 1.f / (1.f + __expf(-af_));
            float og = 1.f / (1.f + __expf(-ao));
            float gv = tanhf(ag);
            const int idx = n * 512 + hcol;
            float cn = fg * c[idx] + ig * gv;
            float hn = og * tanhf(cn);
            c[idx] = cn;
            u16 hbv = f2b(hn);
            hb_out[idx] = hbv;
            hallbt[idx] = hbv;
            hnew[rl][lm] = hbv;
        }
    }
    __syncthreads();
    {
        const int r = tid >> 4, p = tid & 15, n = r0 + r;
        const u16* ap = Ab + (size_t)n * 8192 + p * 512 + hc0;
        float s = 0.f;
#pragma unroll
        for (int j = 0; j < 16; j++) s += b2f(hnew[r][j]) * b2f(ap[j]);
        scp_out[cg * 4096 + n * 16 + p] = s;
    }
}

// ---------------------------------------------------------------------------
// K6 (MFMA v4): vocab + fused logsumexp. m97-style 2-barrier LDS-staged GEMM.
// grid (40 ct, 64 rt); 512 thr = 8 waves (2 row x 4 col); tile 128x256, BK=32.
// Both A (hallb rows) and B (Wvt rows) staged via global_load_lds width-16.
__global__ __launch_bounds__(512) void vocab_mfma_kernel(
    const u16* __restrict__ hallb, const u16* __restrict__ Wvt,
    const float* __restrict__ bv, const int* __restrict__ caps,
    float* __restrict__ pmax, float* __restrict__ psum, float* __restrict__ tgt)
{
    const int ct = blockIdx.x, rt = blockIdx.y;
    const int tid = threadIdx.x, w = tid >> 6, lane = tid & 63;
    const int wr = w >> 2, wc = w & 3;                // 2 x 4 wave grid
    const int r0 = rt * 128, c0 = ct * 256;
    const int lm = lane & 15, lkq = lane >> 4, lk = lkq * 8;

    __shared__ u16 As[128 * 32];                      // 8 KB  [row][k] linear
    __shared__ u16 Bs[256 * 32];                      // 16 KB [col][k] linear
    __shared__ int tvs[128];
    __shared__ float cm[128][4], cs[128][4];

    if (tid < 128) {
        int row = r0 + tid;                           // row = t*256 + n
        tvs[tid] = caps[(row & 255) * 33 + (row >> 8) + 1];
    }

    f32x4 acc[4][4];
#pragma unroll
    for (int mt = 0; mt < 4; mt++)
#pragma unroll
        for (int nt = 0; nt < 4; nt++) acc[mt][nt] = (f32x4){0.f, 0.f, 0.f, 0.f};

    // staging map: chunk = 64 lanes x 16B; A has 8 chunks (1/wave),
    // B has 16 chunks (2/wave). flat f -> row = f>>2, kpart = (f&3)*8.
    const int fa  = w * 64 + lane;
    const u16* gA  = hallb + (size_t)(r0 + (fa >> 2)) * 512 + (fa & 3) * 8;
    const int fb0 = w * 64 + lane;
    const int fb1 = fb0 + 512;
    const u16* gB0 = Wvt + (size_t)(c0 + (fb0 >> 2)) * 512 + (fb0 & 3) * 8;
    const u16* gB1 = Wvt + (size_t)(c0 + (fb1 >> 2)) * 512 + (fb1 & 3) * 8;
    u16* lA  = &As[w * 512];                          // wave-uniform bases
    u16* lB0 = &Bs[w * 512];
    u16* lB1 = &Bs[(w + 8) * 512];

    for (int kc = 0; kc < 512; kc += 32) {
        gload16(gA  + kc, lA);
        gload16(gB0 + kc, lB0);
        gload16(gB1 + kc, lB1);
        __syncthreads();                              // drains vmcnt+lgkmcnt
        bf16x8 af[4], bfr[4];
#pragma unroll
        for (int mt = 0; mt < 4; mt++)
            af[mt] = *(const bf16x8*)&As[(wr * 64 + mt * 16 + lm) * 32 + lk];
#pragma unroll
        for (int nt = 0; nt < 4; nt++)
            bfr[nt] = *(const bf16x8*)&Bs[(wc * 64 + nt * 16 + lm) * 32 + lk];
#pragma unroll
        for (int nt = 0; nt < 4; nt++)
#pragma unroll
            for (int mt = 0; mt < 4; mt++)
                acc[mt][nt] = __builtin_amdgcn_mfma_f32_16x16x32_bf16(af[mt], bfr[nt], acc[mt][nt], 0, 0, 0);
        __syncthreads();                              // LDS reuse fence
    }

    float bvv[4]; bool vld[4];
#pragma unroll
    for (int nt = 0; nt < 4; nt++) {
        int col = c0 + wc * 64 + nt * 16 + lm;
        vld[nt] = (col < NV);
        bvv[nt] = vld[nt] ? bv[col] : 0.f;
    }
#pragma unroll
    for (int mt = 0; mt < 4; mt++)
#pragma unroll
        for (int r = 0; r < 4; r++) {
            int rloc = wr * 64 + mt * 16 + lkq * 4 + r;
            int row = r0 + rloc;
            int tv = tvs[rloc];
            float vals[4]; float m = -1e30f;
#pragma unroll
            for (int nt = 0; nt < 4; nt++) {
                int col = c0 + wc * 64 + nt * 16 + lm;
                float v = vld[nt] ? (acc[mt][nt][r] + bvv[nt]) : -1e30f;
                vals[nt] = v;
                m = fmaxf(m, v);
                if (col == tv) tgt[row] = v;
            }
#pragma unroll
            for (int mask = 1; mask <= 8; mask <<= 1) m = fmaxf(m, __shfl_xor(m, mask, 64));
            float s = 0.f;
#pragma unroll
            for (int nt = 0; nt < 4; nt++) s += __expf(vals[nt] - m);
#pragma unroll
            for (int mask = 1; mask <= 8; mask <<= 1) s += __shfl_xor(s, mask, 64);
            if (lm == 0) { cm[rloc][wc] = m; cs[rloc][wc] = s; }
        }
    __syncthreads();
    if (tid < 128) {
        float M = -1e30f;
#pragma unroll
        for (int q = 0; q < 4; q++) M = fmaxf(M, cm[tid][q]);
        float S = 0.f;
#pragma unroll
        for (int q = 0; q < 4; q++) S += cs[tid][q] * __expf(cm[tid][q] - M);
        int row = r0 + tid;
        pmax[row * VT_N + ct] = M;
        psum[row * VT_N + ct] = S;
    }
}

// ---------------------------------------------------------------------------
__global__ __launch_bounds__(256) void loss_reduce_kernel(
    const float* __restrict__ pmax, const float* __restrict__ psum,
    const float* __restrict__ tgt, const int* __restrict__ caps,
    float* __restrict__ loss)
{
    const int row = blockIdx.x * 256 + threadIdx.x;
    float nll = 0.f;
    const int t = row >> 8, n = row & 255;
    const int tv = caps[n * 33 + t + 1];
    if (tv != 0) {
        float M = -1e30f;
#pragma unroll
        for (int vt = 0; vt < VT_N; vt++) M = fmaxf(M, pmax[row * VT_N + vt]);
        float S = 0.f;
#pragma unroll
        for (int vt = 0; vt < VT_N; vt++) S += psum[row * VT_N + vt] * __expf(pmax[row * VT_N + vt] - M);
        nll = logf(S) + M - tgt[row];
    }
#pragma unroll
    for (int off = 32; off; off >>= 1) nll += __shfl_down(nll, off, 64);
    __shared__ float r4[4];
    if ((threadIdx.x & 63) == 0) r4[threadIdx.x >> 6] = nll;
    __syncthreads();
    if (threadIdx.x == 0)
        atomicAdd(loss, (r4[0] + r4[1] + r4[2] + r4[3]) * (1.f / 256.f));
}

__global__ void finalize_kernel(const float* __restrict__ loss, float* __restrict__ out)
{
    if (threadIdx.x == 0 && blockIdx.x == 0) out[0] = loss[0];
}

// ---------------------------------------------------------------------------
extern "C" void kernel_launch(void* const* d_in, const int* in_sizes, int n_in,
                              void* d_out, int out_size, void* d_ws, size_t ws_size,
                              hipStream_t stream) {
    const float* feats = (const float*)d_in[0];
    const int*   caps  = (const int*)d_in[1];
    const float* Wp    = (const float*)d_in[2];
    const float* bp    = (const float*)d_in[3];
    const float* We    = (const float*)d_in[4];
    const float* Wx    = (const float*)d_in[5];
    const float* Wh    = (const float*)d_in[6];
    const float* Wattn = (const float*)d_in[7];
    const float* bb    = (const float*)d_in[8];
    const float* Wv    = (const float*)d_in[9];
    const float* bv    = (const float*)d_in[10];

    char* ws = (char*)d_ws;
    float* c     = (float*)(ws + B_C);
    float* scp0  = (float*)(ws + B_SCP);
    float* scp1  = scp0 + (size_t)32 * 4096;
    float* pmax  = (float*)(ws + B_PMAX);
    float* psum  = (float*)(ws + B_PSUM);
    float* tgt   = (float*)(ws + B_TGT);
    float* loss  = (float*)(ws + B_LOSS);
    u16*   Ab    = (u16*)(ws + B_AB);
    u16*   xpb   = (u16*)(ws + B_XPB);
    u16*   hallb = (u16*)(ws + B_HALLB);
    u16*   wvt   = (u16*)(ws + B_WVT);
    u16*   wxt   = (u16*)(ws + B_WXT);
    u16*   what  = (u16*)(ws + B_WHAT);
    u16*   hb[2] = { (u16*)(ws + B_HB0), (u16*)(ws + B_HB1) };
    u16*   preaw = (u16*)(ws + B_PREAW);
    u16*   fT    = wvt;      // alias: dead before tconv(Wv) overwrites
    u16*   WpT   = xpb;      // alias: dead before xp_mfma overwrites

    hipMemsetAsync(loss, 0, sizeof(float), stream);

    // --- proj path (MFMA): feats^T -> GEMM -> Ab, mean -> c0/hb0 ---
    ftrans_kernel<<<dim3(20, 256), 256, 0, stream>>>(feats, fT);
    tconv_kernel<<<dim3(8, 20), 256, 0, stream>>>(Wp, WpT, 1280, 512, 512, 1280, 0);
    proj_gemm_kernel<<<64, 256, 0, stream>>>(fT, WpT, bp, Ab);
    projmean_kernel<<<256, 256, 0, stream>>>(Ab, c, hb[0]);

    // --- weight preps (overwrite fT / WpT aliases) ---
    tconv_kernel<<<dim3(160, 8), 256, 0, stream>>>(Wv, wvt, 512, NV, NVP, 512, 0);
    tconv_kernel<<<dim3(32, 4),  256, 0, stream>>>(Wx, wxt, 256, 2048, 2048, 256, 0);
    tconv_kernel<<<dim3(32, 8),  256, 0, stream>>>(Wh, what, 512, 2048, 2048, 1024, 0);
    tconv_kernel<<<dim3(32, 8),  256, 0, stream>>>(Wattn, what, 512, 2048, 2048, 1024, 512);
    xp_mfma_kernel<<<dim3(4, 128), 256, 0, stream>>>(caps, We, wxt, bb, xpb);
    preaw_mfma_kernel<<<dim3(4, 64), 256, 0, stream>>>(Ab, what, preaw);
    score_init_kernel<<<256, 64, 0, stream>>>(hb[0], Ab, scp0);

    for (int t = 0; t < NT; t++) {
        const int in = t & 1;
        gates_fused_kernel<<<dim3(16, 32), 256, 0, stream>>>(
            hb[in], in ? scp1 : scp0, what, preaw,
            xpb + (size_t)t * 524288, Ab, c,
            hb[1 - in], hallb + (size_t)t * 131072,
            in ? scp0 : scp1);
    }

    vocab_mfma_kernel<<<dim3(VT_N, 64), 512, 0, stream>>>(
        hallb, wvt, bv, caps, pmax, psum, tgt);
    loss_reduce_kernel<<<32, 256, 0, stream>>>(pmax, psum, tgt, caps, loss);
    finalize_kernel<<<1, 64, 0, stream>>>(loss, (float*)d_out);
}

// Round 2
// 883.519 us; speedup vs baseline: 1.1175x; 1.0166x over previous
//
#include <hip/hip_runtime.h>
#include <hip/hip_bf16.h>

#define NB   256
#define NT   32
#define NV   10000
#define NVP  10240
#define NDF  1280
#define NH   512
#define VT_N 40      // vocab col tiles of 256

typedef short bf16x8 __attribute__((ext_vector_type(8)));
typedef float f32x4  __attribute__((ext_vector_type(4)));
typedef unsigned short u16;

__device__ __forceinline__ float b2f(u16 u) {
    union { unsigned i; float f; } v; v.i = ((unsigned)u) << 16; return v.f;
}
__device__ __forceinline__ u16 f2b(float f) {
    union { float f; unsigned i; } v; v.f = f;
    unsigned r = v.i + 0x7FFF + ((v.i >> 16) & 1);   // RNE
    return (u16)(r >> 16);
}

// async global->LDS, 16B per lane; lds dest must be wave-uniform base
__device__ __forceinline__ void gload16(const u16* g, u16* l) {
    __builtin_amdgcn_global_load_lds(
        (const __attribute__((address_space(1))) void*)g,
        (__attribute__((address_space(3))) void*)l, 16, 0, 0);
}

// ---------------- workspace layout (byte offsets, 16-aligned) --------------
static const size_t B_C     = 0;                                  // [256][512] f32 cell
static const size_t B_SCP   = B_C     + (size_t)256*512*4;        // [2][32][256][16] f32
static const size_t B_PMAX  = B_SCP   + (size_t)2*32*256*16*4;    // [8192][40] f32
static const size_t B_PSUM  = B_PMAX  + (size_t)8192*VT_N*4;      // [8192][40] f32
static const size_t B_TGT   = B_PSUM  + (size_t)8192*VT_N*4;      // [8192] f32
static const size_t B_LOSS  = B_TGT   + (size_t)8192*4;           // [1] f32
static const size_t B_AB    = B_LOSS  + 16;                       // [256][16][512] bf16
static const size_t B_XPB   = B_AB    + (size_t)256*16*512*2;     // [32][256][2048] bf16
static const size_t B_HALLB = B_XPB   + (size_t)32*256*2048*2;    // [32][256][512] bf16
static const size_t B_WVT   = B_HALLB + (size_t)32*256*512*2;     // [10240][512] bf16
static const size_t B_WXT   = B_WVT   + (size_t)10240*512*2;      // [2048][256] bf16
static const size_t B_WHAT  = B_WXT   + (size_t)2048*256*2;       // [2048][1024] bf16
static const size_t B_HB0   = B_WHAT  + (size_t)2048*1024*2;      // [256][512] bf16 h ping
static const size_t B_HB1   = B_HB0   + (size_t)256*512*2;        // [256][512] bf16 h pong
static const size_t B_PREAW = B_HB1   + (size_t)256*512*2;        // [16*256][2048] bf16
// Aliases (prep-only, dead before overwriter runs):
//   fT  (4096x1280 bf16 = 10.49 MB) lives at B_WVT  (wvt written later)
//   WpT (512x1280 bf16 = 1.31 MB)   lives at B_XPB  (xpb written later)

// ---------------------------------------------------------------------------
// T0: transpose+convert: src f32 [K][N] -> dst bf16 [Npad][ldK] at koff.
__global__ __launch_bounds__(256) void tconv_kernel(
    const float* __restrict__ src, u16* __restrict__ dst,
    int K, int N, int Npad, int ldK, int koff)
{
    __shared__ u16 tile[64][65];
    const int k0 = blockIdx.y * 64, n0 = blockIdx.x * 64, tid = threadIdx.x;
#pragma unroll
    for (int i = 0; i < 16; i++) {
        int idx = tid + i * 256;
        int kk = idx >> 6, nn = idx & 63;
        int n = n0 + nn;
        float v = (n < N) ? src[(size_t)(k0 + kk) * N + n] : 0.f;
        tile[kk][nn] = f2b(v);
    }
    __syncthreads();
#pragma unroll
    for (int i = 0; i < 16; i++) {
        int idx = tid + i * 256;
        int nn = idx >> 6, kk = idx & 63;
        int n = n0 + nn;
        if (n < Npad) dst[(size_t)n * ldK + koff + k0 + kk] = tile[kk][nn];
    }
}

// ---------------------------------------------------------------------------
// P1: feats f32 [n][c][p16] -> fT bf16 [n*16+p][1280]. grid (20 cch, 256 n).
__global__ __launch_bounds__(256) void ftrans_kernel(
    const float* __restrict__ feats, u16* __restrict__ fT)
{
    const int cch = blockIdx.x, n = blockIdx.y, tid = threadIdx.x;
    __shared__ u16 lt[64][17];
    const int c0 = cch * 64;
    const int c = tid >> 2, p4 = (tid & 3) * 4;
    float4 v = *(const float4*)(feats + (size_t)n * 20480 + (size_t)(c0 + c) * 16 + p4);
    lt[c][p4] = f2b(v.x); lt[c][p4 + 1] = f2b(v.y);
    lt[c][p4 + 2] = f2b(v.z); lt[c][p4 + 3] = f2b(v.w);
    __syncthreads();
    const int p = tid >> 4, cg = tid & 15;
    ushort4 o;
    o.x = lt[cg * 4 + 0][p]; o.y = lt[cg * 4 + 1][p];
    o.z = lt[cg * 4 + 2][p]; o.w = lt[cg * 4 + 3][p];
    *(ushort4*)(fT + (size_t)(n * 16 + p) * 1280 + c0 + cg * 4) = o;
}

// ---------------------------------------------------------------------------
// P2 (MFMA): Ab[row][col] = fT[row] @ WpT^T + bp, row = n*16+p. grid 64 rt.
__global__ __launch_bounds__(256) void proj_gemm_kernel(
    const u16* __restrict__ fT, const u16* __restrict__ WpT,
    const float* __restrict__ bp, u16* __restrict__ Ab)
{
    const int rt = blockIdx.x;
    const int tid = threadIdx.x, w = tid >> 6, lane = tid & 63;
    const int r0 = rt * 64;
    const int lm = lane & 15, lkq = lane >> 4, lk = lkq * 8;
    const int nbase = w * 128;

    f32x4 acc[4][8];
#pragma unroll
    for (int mt = 0; mt < 4; mt++)
#pragma unroll
        for (int nt = 0; nt < 8; nt++) acc[mt][nt] = (f32x4){0.f, 0.f, 0.f, 0.f};

    for (int kc = 0; kc < 1280; kc += 32) {
        bf16x8 af[4];
#pragma unroll
        for (int mt = 0; mt < 4; mt++)
            af[mt] = *(const bf16x8*)(fT + (size_t)(r0 + mt * 16 + lm) * 1280 + kc + lk);
#pragma unroll
        for (int nt = 0; nt < 8; nt++) {
            bf16x8 bfg = *(const bf16x8*)(WpT + (size_t)(nbase + nt * 16 + lm) * 1280 + kc + lk);
#pragma unroll
            for (int mt = 0; mt < 4; mt++)
                acc[mt][nt] = __builtin_amdgcn_mfma_f32_16x16x32_bf16(af[mt], bfg, acc[mt][nt], 0, 0, 0);
        }
    }
    float bbv[8];
#pragma unroll
    for (int nt = 0; nt < 8; nt++) bbv[nt] = bp[nbase + nt * 16 + lm];
#pragma unroll
    for (int mt = 0; mt < 4; mt++)
#pragma unroll
        for (int nt = 0; nt < 8; nt++)
#pragma unroll
            for (int r = 0; r < 4; r++) {
                int row = r0 + mt * 16 + lkq * 4 + r;
                int col = nbase + nt * 16 + lm;
                Ab[(size_t)row * 512 + col] = f2b(acc[mt][nt][r] + bbv[nt]);
            }
}

// ---------------------------------------------------------------------------
// P3: c0 = h0 = mean_p Ab (f32); hb0 = bf16(h0). grid 256.
__global__ __launch_bounds__(256) void projmean_kernel(
    const u16* __restrict__ Ab, float* __restrict__ c0, u16* __restrict__ hb0)
{
    const int n = blockIdx.x, tid = threadIdx.x;
    const int col0 = tid, col1 = tid + 256;
    float s0 = 0.f, s1 = 0.f;
#pragma unroll
    for (int p = 0; p < 16; p++) {
        const u16* ap = Ab + ((size_t)n * 16 + p) * 512;
        s0 += b2f(ap[col0]);
        s1 += b2f(ap[col1]);
    }
    s0 *= 0.0625f; s1 *= 0.0625f;
    c0[n * 512 + col0] = s0;  c0[n * 512 + col1] = s1;
    hb0[(size_t)n * 512 + col0] = f2b(s0);
    hb0[(size_t)n * 512 + col1] = f2b(s1);
}

// ---------------------------------------------------------------------------
// K2 (MFMA): xpb = embed@Wx + b  (bf16), rows stored as [t][n]
__global__ __launch_bounds__(256) void xp_mfma_kernel(
    const int* __restrict__ caps, const float* __restrict__ We,
    const u16* __restrict__ Wxt, const float* __restrict__ bb,
    u16* __restrict__ xpb)
{
    const int ct = blockIdx.x, rt = blockIdx.y;
    const int tid = threadIdx.x, w = tid >> 6, lane = tid & 63;
    const int r0 = rt * 64;
    const int lm = lane & 15, lkq = lane >> 4, lk = lkq * 8;
    const int nbase = ct * 512 + w * 128;

    int capm[4];
#pragma unroll
    for (int mt = 0; mt < 4; mt++) {
        int row = r0 + mt * 16 + lm;
        capm[mt] = caps[(row >> 5) * 33 + (row & 31)];
    }
    f32x4 acc[4][8];
#pragma unroll
    for (int mt = 0; mt < 4; mt++)
#pragma unroll
        for (int nt = 0; nt < 8; nt++) acc[mt][nt] = (f32x4){0.f, 0.f, 0.f, 0.f};

    for (int kc = 0; kc < 256; kc += 32) {
        bf16x8 af[4];
#pragma unroll
        for (int mt = 0; mt < 4; mt++) {
            const float* ap = We + (size_t)capm[mt] * 256 + kc + lk;
            float4 f0 = *(const float4*)ap;
            float4 f1 = *(const float4*)(ap + 4);
            bf16x8 t;
            t[0] = (short)f2b(f0.x); t[1] = (short)f2b(f0.y);
            t[2] = (short)f2b(f0.z); t[3] = (short)f2b(f0.w);
            t[4] = (short)f2b(f1.x); t[5] = (short)f2b(f1.y);
            t[6] = (short)f2b(f1.z); t[7] = (short)f2b(f1.w);
            af[mt] = t;
        }
#pragma unroll
        for (int nt = 0; nt < 8; nt++) {
            bf16x8 bfg = *(const bf16x8*)(Wxt + (size_t)(nbase + nt * 16 + lm) * 256 + kc + lk);
#pragma unroll
            for (int mt = 0; mt < 4; mt++)
                acc[mt][nt] = __builtin_amdgcn_mfma_f32_16x16x32_bf16(af[mt], bfg, acc[mt][nt], 0, 0, 0);
        }
    }
    float bbv[8];
#pragma unroll
    for (int nt = 0; nt < 8; nt++) bbv[nt] = bb[nbase + nt * 16 + lm];
#pragma unroll
    for (int mt = 0; mt < 4; mt++)
#pragma unroll
        for (int nt = 0; nt < 8; nt++)
#pragma unroll
            for (int r = 0; r < 4; r++) {
                int row = r0 + mt * 16 + lkq * 4 + r;   // row = n*32 + t
                int col = nbase + nt * 16 + lm;
                float v = acc[mt][nt][r] + bbv[nt];
                xpb[((size_t)(row & 31) * 256 + (row >> 5)) * 2048 + col] = f2b(v);
            }
}

// ---------------------------------------------------------------------------
// K3 (MFMA, once): PreAW[p*256+n][col] = A[n,p,:] @ Wattn  (bf16 out)
__global__ __launch_bounds__(256) void preaw_mfma_kernel(
    const u16* __restrict__ Ab, const u16* __restrict__ what,
    u16* __restrict__ preaw)
{
    const int ct = blockIdx.x, rt = blockIdx.y;
    const int tid = threadIdx.x, w = tid >> 6, lane = tid & 63;
    const int r0 = rt * 64;
    const int lm = lane & 15, lkq = lane >> 4, lk = lkq * 8;
    const int nbase = ct * 512 + w * 128;

    f32x4 acc[4][8];
#pragma unroll
    for (int mt = 0; mt < 4; mt++)
#pragma unroll
        for (int nt = 0; nt < 8; nt++) acc[mt][nt] = (f32x4){0.f, 0.f, 0.f, 0.f};

    for (int kc = 0; kc < 512; kc += 32) {
        bf16x8 af[4];
#pragma unroll
        for (int mt = 0; mt < 4; mt++) {
            int row = r0 + mt * 16 + lm;                  // row = p*256+n
            af[mt] = *(const bf16x8*)(Ab + ((size_t)(row & 255) * 16 + (row >> 8)) * 512 + kc + lk);
        }
#pragma unroll
        for (int nt = 0; nt < 8; nt++) {
            bf16x8 bfg = *(const bf16x8*)(what + (size_t)(nbase + nt * 16 + lm) * 1024 + 512 + kc + lk);
#pragma unroll
            for (int mt = 0; mt < 4; mt++)
                acc[mt][nt] = __builtin_amdgcn_mfma_f32_16x16x32_bf16(af[mt], bfg, acc[mt][nt], 0, 0, 0);
        }
    }
#pragma unroll
    for (int mt = 0; mt < 4; mt++)
#pragma unroll
        for (int nt = 0; nt < 8; nt++)
#pragma unroll
            for (int r = 0; r < 4; r++) {
                int row = r0 + mt * 16 + lkq * 4 + r;
                int col = nbase + nt * 16 + lm;
                preaw[(size_t)row * 2048 + col] = f2b(acc[mt][nt][r]);
            }
}

// ---------------------------------------------------------------------------
// K4 (once): scores for t=0: scp[0][n][p] = h0[n]·A[n,p]; zero cg>0
__global__ __launch_bounds__(64) void score_init_kernel(
    const u16* __restrict__ hb0, const u16* __restrict__ Ab,
    float* __restrict__ scp)
{
    const int n = blockIdx.x, lane = threadIdx.x;
    const u16* hp = hb0 + (size_t)n * 512 + lane * 8;
    ushort4 h0 = *(const ushort4*)hp, h1 = *(const ushort4*)(hp + 4);
    float hv0 = b2f(h0.x), hv1 = b2f(h0.y), hv2 = b2f(h0.z), hv3 = b2f(h0.w);
    float hv4 = b2f(h1.x), hv5 = b2f(h1.y), hv6 = b2f(h1.z), hv7 = b2f(h1.w);
    float mine = 0.f;
#pragma unroll
    for (int p = 0; p < 16; p++) {
        const u16* ap = Ab + (size_t)n * 8192 + p * 512 + lane * 8;
        ushort4 a0 = *(const ushort4*)ap, a1 = *(const ushort4*)(ap + 4);
        float s = hv0*b2f(a0.x) + hv1*b2f(a0.y) + hv2*b2f(a0.z) + hv3*b2f(a0.w)
                + hv4*b2f(a1.x) + hv5*b2f(a1.y) + hv6*b2f(a1.z) + hv7*b2f(a1.w);
#pragma unroll
        for (int mask = 1; mask <= 32; mask <<= 1) s += __shfl_xor(s, mask, 64);
        if (lane == p) mine = s;
    }
    if (lane < 16) scp[n * 16 + lane] = mine;
    for (int i = lane; i < 31 * 16; i += 64)
        scp[(1 + (i >> 4)) * 4096 + n * 16 + (i & 15)] = 0.f;
}

// ---------------------------------------------------------------------------
// K5 (per step): softmax(scores) -> gates MFMA + PreAW attn + nonlin ->
// c,h update -> score partials for t+1. grid (16 rt, 32 cg), 4 waves.
__global__ __launch_bounds__(256) void gates_fused_kernel(
    const u16* __restrict__ hb_in, const float* __restrict__ scp_in,
    const u16* __restrict__ what, const u16* __restrict__ preaw,
    const u16* __restrict__ xpt, const u16* __restrict__ Ab,
    float* __restrict__ c, u16* __restrict__ hb_out,
    u16* __restrict__ hallbt, float* __restrict__ scp_out)
{
    const int rt = blockIdx.x, cg = blockIdx.y;
    const int tid = threadIdx.x, ty = tid >> 6, lane = tid & 63;
    const int lm = lane & 15, lkq = lane >> 4, lk = lkq * 8;
    const int r0 = rt * 16, hc0 = cg * 16;

    __shared__ u16 hs[16 * 520];
    __shared__ float sred[16][17];
    __shared__ float wts[16][17];
    __shared__ float gred[3][64][4];
    __shared__ u16 hnew[16][16];

#pragma unroll
    for (int i = 0; i < 8; i++) {
        int fid = tid + i * 256;
        int r = fid >> 7, c4 = fid & 127;
        *(ushort4*)&hs[r * 520 + c4 * 4] =
            *(const ushort4*)(hb_in + (size_t)(r0 + r) * 512 + c4 * 4);
    }
    {
        const int r = tid >> 4, p = tid & 15;
        float s = 0.f;
#pragma unroll
        for (int g = 0; g < 32; g++) s += scp_in[g * 4096 + (r0 + r) * 16 + p];
        sred[r][p] = s * 0.04419417382415922f;
    }
    __syncthreads();
    {
        const int r = tid >> 4, p = tid & 15;
        float m = -1e30f;
#pragma unroll
        for (int q = 0; q < 16; q++) m = fmaxf(m, sred[r][q]);
        float su = 0.f;
#pragma unroll
        for (int q = 0; q < 16; q++) su += __expf(sred[r][q] - m);
        wts[r][p] = __expf(sred[r][p] - m) / su;
    }
    __syncthreads();

    f32x4 acc = (f32x4){0.f, 0.f, 0.f, 0.f};
    const u16* brow = what + (size_t)(ty * 512 + hc0 + lm) * 1024 + lk;
    const u16* arow = &hs[lm * 520 + lk];
    for (int kc = 0; kc < 512; kc += 32) {
        bf16x8 af = *(const bf16x8*)(arow + kc);
        bf16x8 bfg = *(const bf16x8*)(brow + kc);
        acc = __builtin_amdgcn_mfma_f32_16x16x32_bf16(af, bfg, acc, 0, 0, 0);
    }
    float val[4];
#pragma unroll
    for (int r = 0; r < 4; r++) {
        const int rl = lkq * 4 + r, n = r0 + rl;
        const int col = ty * 512 + hc0 + lm;
        float s = acc[r] + b2f(xpt[(size_t)n * 2048 + col]);
#pragma unroll
        for (int p = 0; p < 16; p++)
            s += wts[rl][p] * b2f(preaw[((size_t)p * 256 + n) * 2048 + col]);
        val[r] = s;
    }
    if (ty > 0) {
#pragma unroll
        for (int r = 0; r < 4; r++) gred[ty - 1][lane][r] = val[r];
    }
    __syncthreads();
    if (ty == 0) {
#pragma unroll
        for (int r = 0; r < 4; r++) {
            const int rl = lkq * 4 + r, n = r0 + rl;
            const int hcol = hc0 + lm;
            float ai  = val[r];
            float af_ = gred[0][lane][r];
            float ao  = gred[1][lane][r];
            float ag  = gred[2][lane][r];
            float ig = 1.f / (1.f + __expf(-ai));
            float fg = 1.f / (1.f + __expf(-af_));
            float og = 1.f / (1.f + __expf(-ao));
            float gv = tanhf(ag);
            const int idx = n * 512 + hcol;
            float cn = fg * c[idx] + ig * gv;
            float hn = og * tanhf(cn);
            c[idx] = cn;
            u16 hbv = f2b(hn);
            hb_out[idx] = hbv;
            hallbt[idx] = hbv;
            hnew[rl][lm] = hbv;
        }
    }
    __syncthreads();
    {
        const int r = tid >> 4, p = tid & 15, n = r0 + r;
        const u16* ap = Ab + (size_t)n * 8192 + p * 512 + hc0;
        float s = 0.f;
#pragma unroll
        for (int j = 0; j < 16; j++) s += b2f(hnew[r][j]) * b2f(ap[j]);
        scp_out[cg * 4096 + n * 16 + p] = s;
    }
}

// ---------------------------------------------------------------------------
// K6 (MFMA v5): vocab + fused logsumexp. 2-phase double-buffered pipeline:
// issue next tile's global_load_lds BEFORE computing current; counted
// s_waitcnt vmcnt(3) + raw barriers (no vmcnt(0) drain in the loop).
// LDS swizzle slot(r,kq)=r*4+(kq^((r>>1)&3)) applied on BOTH sides
// (pre-swizzled global source + swizzled ds_read) -> 2-way banks (free),
// 64B-line global coalescing preserved (XOR permutes quarters in-line).
// grid (40 ct, 64 rt); 512 thr = 8 waves (2x4); tile 128x256, BK=32.
__global__ __launch_bounds__(512) void vocab_mfma_kernel(
    const u16* __restrict__ hallb, const u16* __restrict__ Wvt,
    const float* __restrict__ bv, const int* __restrict__ caps,
    float* __restrict__ pmax, float* __restrict__ psum, float* __restrict__ tgt)
{
    const int ct = blockIdx.x, rt = blockIdx.y;
    const int tid = threadIdx.x, w = tid >> 6, lane = tid & 63;
    const int wr = w >> 2, wc = w & 3;                // 2 x 4 wave grid
    const int r0 = rt * 128, c0 = ct * 256;
    const int lm = lane & 15, lkq = lane >> 4;
    const int swz = lkq ^ ((lm >> 1) & 3);            // read-side XOR

    __shared__ u16 As[2][512 * 8];                    // 2 x 8 KB, 16B units
    __shared__ u16 Bs[2][1024 * 8];                   // 2 x 16 KB
    __shared__ int tvs[128];
    __shared__ float cm[128][4], cs[128][4];

    if (tid < 128) {
        int row = r0 + tid;                           // row = t*256 + n
        tvs[tid] = caps[(row & 255) * 33 + (row >> 8) + 1];
    }

    f32x4 acc[4][4];
#pragma unroll
    for (int mt = 0; mt < 4; mt++)
#pragma unroll
        for (int nt = 0; nt < 4; nt++) acc[mt][nt] = (f32x4){0.f, 0.f, 0.f, 0.f};

    // staging: LDS written linearly (unit = w*64+lane, 16B each); global
    // source pre-swizzled so element (r, kq=slot^((r>>1)&3)) lands at slot.
    const int sA = w * 64 + lane;                     // 0..511
    const int rA = sA >> 2, kA = (sA & 3) ^ ((rA >> 1) & 3);
    const u16* gA = hallb + (size_t)(r0 + rA) * 512 + kA * 8;
    const int sB0 = w * 64 + lane, sB1 = sB0 + 512;   // 0..1023
    const int cB0 = sB0 >> 2, kB0 = (sB0 & 3) ^ ((cB0 >> 1) & 3);
    const int cB1 = sB1 >> 2, kB1 = (sB1 & 3) ^ ((cB1 >> 1) & 3);
    const u16* gB0 = Wvt + (size_t)(c0 + cB0) * 512 + kB0 * 8;
    const u16* gB1 = Wvt + (size_t)(c0 + cB1) * 512 + kB1 * 8;

    auto stage = [&](int buf, int kc) {
        gload16(gA + kc, &As[buf][w * 512]);
        gload16(gB0 + kc, &Bs[buf][w * 512]);
        gload16(gB1 + kc, &Bs[buf][(w + 8) * 512]);
    };
    auto compute = [&](int buf) {
        bf16x8 af[4], bfr[4];
#pragma unroll
        for (int mt = 0; mt < 4; mt++)
            af[mt] = *(const bf16x8*)&As[buf][((wr * 64 + mt * 16 + lm) * 4 + swz) * 8];
#pragma unroll
        for (int nt = 0; nt < 4; nt++)
            bfr[nt] = *(const bf16x8*)&Bs[buf][((wc * 64 + nt * 16 + lm) * 4 + swz) * 8];
#pragma unroll
        for (int nt = 0; nt < 4; nt++)
#pragma unroll
            for (int mt = 0; mt < 4; mt++)
                acc[mt][nt] = __builtin_amdgcn_mfma_f32_16x16x32_bf16(af[mt], bfr[nt], acc[mt][nt], 0, 0, 0);
    };

    stage(0, 0);
#pragma unroll 1
    for (int t = 0; t < 15; ++t) {
        const int cur = t & 1;
        stage(cur ^ 1, (t + 1) * 32);                 // prefetch next K-tile
        asm volatile("s_waitcnt vmcnt(3)" ::: "memory");  // own current-buf loads done
        __builtin_amdgcn_s_barrier();                 // all waves' writes visible
        compute(cur);
        __builtin_amdgcn_s_barrier();                 // reads done before overwrite
    }
    asm volatile("s_waitcnt vmcnt(0)" ::: "memory");
    __builtin_amdgcn_s_barrier();
    compute(1);                                       // t=15 -> buf 1

    float bvv[4]; bool vld[4];
#pragma unroll
    for (int nt = 0; nt < 4; nt++) {
        int col = c0 + wc * 64 + nt * 16 + lm;
        vld[nt] = (col < NV);
        bvv[nt] = vld[nt] ? bv[col] : 0.f;
    }
#pragma unroll
    for (int mt = 0; mt < 4; mt++)
#pragma unroll
        for (int r = 0; r < 4; r++) {
            int rloc = wr * 64 + mt * 16 + lkq * 4 + r;
            int row = r0 + rloc;
            int tv = tvs[rloc];
            float vals[4]; float m = -1e30f;
#pragma unroll
            for (int nt = 0; nt < 4; nt++) {
                int col = c0 + wc * 64 + nt * 16 + lm;
                float v = vld[nt] ? (acc[mt][nt][r] + bvv[nt]) : -1e30f;
                vals[nt] = v;
                m = fmaxf(m, v);
                if (col == tv) tgt[row] = v;
            }
#pragma unroll
            for (int mask = 1; mask <= 8; mask <<= 1) m = fmaxf(m, __shfl_xor(m, mask, 64));
            float s = 0.f;
#pragma unroll
            for (int nt = 0; nt < 4; nt++) s += __expf(vals[nt] - m);
#pragma unroll
            for (int mask = 1; mask <= 8; mask <<= 1) s += __shfl_xor(s, mask, 64);
            if (lm == 0) { cm[rloc][wc] = m; cs[rloc][wc] = s; }
        }
    __syncthreads();
    if (tid < 128) {
        float M = -1e30f;
#pragma unroll
        for (int q = 0; q < 4; q++) M = fmaxf(M, cm[tid][q]);
        float S = 0.f;
#pragma unroll
        for (int q = 0; q < 4; q++) S += cs[tid][q] * __expf(cm[tid][q] - M);
        int row = r0 + tid;
        pmax[row * VT_N + ct] = M;
        psum[row * VT_N + ct] = S;
    }
}

// ---------------------------------------------------------------------------
__global__ __launch_bounds__(256) void loss_reduce_kernel(
    const float* __restrict__ pmax, const float* __restrict__ psum,
    const float* __restrict__ tgt, const int* __restrict__ caps,
    float* __restrict__ loss)
{
    const int row = blockIdx.x * 256 + threadIdx.x;
    float nll = 0.f;
    const int t = row >> 8, n = row & 255;
    const int tv = caps[n * 33 + t + 1];
    if (tv != 0) {
        float M = -1e30f;
#pragma unroll
        for (int vt = 0; vt < VT_N; vt++) M = fmaxf(M, pmax[row * VT_N + vt]);
        float S = 0.f;
#pragma unroll
        for (int vt = 0; vt < VT_N; vt++) S += psum[row * VT_N + vt] * __expf(pmax[row * VT_N + vt] - M);
        nll = logf(S) + M - tgt[row];
    }
#pragma unroll
    for (int off = 32; off; off >>= 1) nll += __shfl_down(nll, off, 64);
    __shared__ float r4[4];
    if ((threadIdx.x & 63) == 0) r4[threadIdx.x >> 6] = nll;
    __syncthreads();
    if (threadIdx.x == 0)
        atomicAdd(loss, (r4[0] + r4[1] + r4[2] + r4[3]) * (1.f / 256.f));
}

__global__ void finalize_kernel(const float* __restrict__ loss, float* __restrict__ out)
{
    if (threadIdx.x == 0 && blockIdx.x == 0) out[0] = loss[0];
}

// ---------------------------------------------------------------------------
extern "C" void kernel_launch(void* const* d_in, const int* in_sizes, int n_in,
                              void* d_out, int out_size, void* d_ws, size_t ws_size,
                              hipStream_t stream) {
    const float* feats = (const float*)d_in[0];
    const int*   caps  = (const int*)d_in[1];
    const float* Wp    = (const float*)d_in[2];
    const float* bp    = (const float*)d_in[3];
    const float* We    = (const float*)d_in[4];
    const float* Wx    = (const float*)d_in[5];
    const float* Wh    = (const float*)d_in[6];
    const float* Wattn = (const float*)d_in[7];
    const float* bb    = (const float*)d_in[8];
    const float* Wv    = (const float*)d_in[9];
    const float* bv    = (const float*)d_in[10];

    char* ws = (char*)d_ws;
    float* c     = (float*)(ws + B_C);
    float* scp0  = (float*)(ws + B_SCP);
    float* scp1  = scp0 + (size_t)32 * 4096;
    float* pmax  = (float*)(ws + B_PMAX);
    float* psum  = (float*)(ws + B_PSUM);
    float* tgt   = (float*)(ws + B_TGT);
    float* loss  = (float*)(ws + B_LOSS);
    u16*   Ab    = (u16*)(ws + B_AB);
    u16*   xpb   = (u16*)(ws + B_XPB);
    u16*   hallb = (u16*)(ws + B_HALLB);
    u16*   wvt   = (u16*)(ws + B_WVT);
    u16*   wxt   = (u16*)(ws + B_WXT);
    u16*   what  = (u16*)(ws + B_WHAT);
    u16*   hb[2] = { (u16*)(ws + B_HB0), (u16*)(ws + B_HB1) };
    u16*   preaw = (u16*)(ws + B_PREAW);
    u16*   fT    = wvt;      // alias: dead before tconv(Wv) overwrites
    u16*   WpT   = xpb;      // alias: dead before xp_mfma overwrites

    hipMemsetAsync(loss, 0, sizeof(float), stream);

    // --- proj path (MFMA): feats^T -> GEMM -> Ab, mean -> c0/hb0 ---
    ftrans_kernel<<<dim3(20, 256), 256, 0, stream>>>(feats, fT);
    tconv_kernel<<<dim3(8, 20), 256, 0, stream>>>(Wp, WpT, 1280, 512, 512, 1280, 0);
    proj_gemm_kernel<<<64, 256, 0, stream>>>(fT, WpT, bp, Ab);
    projmean_kernel<<<256, 256, 0, stream>>>(Ab, c, hb[0]);

    // --- weight preps (overwrite fT / WpT aliases) ---
    tconv_kernel<<<dim3(160, 8), 256, 0, stream>>>(Wv, wvt, 512, NV, NVP, 512, 0);
    tconv_kernel<<<dim3(32, 4),  256, 0, stream>>>(Wx, wxt, 256, 2048, 2048, 256, 0);
    tconv_kernel<<<dim3(32, 8),  256, 0, stream>>>(Wh, what, 512, 2048, 2048, 1024, 0);
    tconv_kernel<<<dim3(32, 8),  256, 0, stream>>>(Wattn, what, 512, 2048, 2048, 1024, 512);
    xp_mfma_kernel<<<dim3(4, 128), 256, 0, stream>>>(caps, We, wxt, bb, xpb);
    preaw_mfma_kernel<<<dim3(4, 64), 256, 0, stream>>>(Ab, what, preaw);
    score_init_kernel<<<256, 64, 0, stream>>>(hb[0], Ab, scp0);

    for (int t = 0; t < NT; t++) {
        const int in = t & 1;
        gates_fused_kernel<<<dim3(16, 32), 256, 0, stream>>>(
            hb[in], in ? scp1 : scp0, what, preaw,
            xpb + (size_t)t * 524288, Ab, c,
            hb[1 - in], hallb + (size_t)t * 131072,
            in ? scp0 : scp1);
    }

    vocab_mfma_kernel<<<dim3(VT_N, 64), 512, 0, stream>>>(
        hallb, wvt, bv, caps, pmax, psum, tgt);
    loss_reduce_kernel<<<32, 256, 0, stream>>>(pmax, psum, tgt, caps, loss);
    finalize_kernel<<<1, 64, 0, stream>>>(loss, (float*)d_out);
}

// Round 4
// 742.734 us; speedup vs baseline: 1.3293x; 1.1895x over previous
//
#include <hip/hip_runtime.h>
#include <hip/hip_bf16.h>

#define NB   256
#define NT   32
#define NV   10000
#define NVP  10240
#define NDF  1280
#define NH   512
#define VT_N 40      // vocab col tiles of 256

typedef short bf16x8 __attribute__((ext_vector_type(8)));
typedef float f32x4  __attribute__((ext_vector_type(4)));
typedef unsigned short u16;

__device__ __forceinline__ float b2f(u16 u) {
    union { unsigned i; float f; } v; v.i = ((unsigned)u) << 16; return v.f;
}
__device__ __forceinline__ u16 f2b(float f) {
    union { float f; unsigned i; } v; v.f = f;
    unsigned r = v.i + 0x7FFF + ((v.i >> 16) & 1);   // RNE
    return (u16)(r >> 16);
}

// async global->LDS, 16B per lane; lds dest must be wave-uniform base
__device__ __forceinline__ void gload16(const u16* g, u16* l) {
    __builtin_amdgcn_global_load_lds(
        (const __attribute__((address_space(1))) void*)g,
        (__attribute__((address_space(3))) void*)l, 16, 0, 0);
}

// ---------------- workspace layout (byte offsets, 16-aligned) --------------
static const size_t B_C     = 0;                                  // [256][512] f32 cell
static const size_t B_SCP   = B_C     + (size_t)256*512*4;        // [2][32][256][16] f32
static const size_t B_PMAX  = B_SCP   + (size_t)2*32*256*16*4;    // [8192][40] f32
static const size_t B_PSUM  = B_PMAX  + (size_t)8192*VT_N*4;      // [8192][40] f32
static const size_t B_TGT   = B_PSUM  + (size_t)8192*VT_N*4;      // [8192] f32
static const size_t B_LOSS  = B_TGT   + (size_t)8192*4;           // [1] f32
static const size_t B_AB    = B_LOSS  + 16;                       // [256][16][512] bf16 (row' = n*16+p)
static const size_t B_XPB   = B_AB    + (size_t)256*16*512*2;     // [32][256][2048] bf16
static const size_t B_HALLB = B_XPB   + (size_t)32*256*2048*2;    // [32][256][512] bf16
static const size_t B_WVT   = B_HALLB + (size_t)32*256*512*2;     // [10240][512] bf16
static const size_t B_WXT   = B_WVT   + (size_t)10240*512*2;      // [2048][256] bf16
static const size_t B_WHAT  = B_WXT   + (size_t)2048*256*2;       // [2048][1024] bf16
static const size_t B_HB0   = B_WHAT  + (size_t)2048*1024*2;      // [256][512] bf16 h ping
static const size_t B_HB1   = B_HB0   + (size_t)256*512*2;        // [256][512] bf16 h pong
static const size_t B_PREAW = B_HB1   + (size_t)256*512*2;        // [256 n][2048 col][16 p] bf16
// Aliases (prep-only, dead before overwriter runs):
//   fT  (4096x1280 bf16 = 10.49 MB) lives at B_WVT  (wvt written later)
//   WpT (512x1280 bf16 = 1.31 MB)   lives at B_XPB  (xpb written later)

// ---------------------------------------------------------------------------
// T0: transpose+convert: src f32 [K][N] -> dst bf16 [Npad][ldK] at koff.
__global__ __launch_bounds__(256) void tconv_kernel(
    const float* __restrict__ src, u16* __restrict__ dst,
    int K, int N, int Npad, int ldK, int koff)
{
    __shared__ u16 tile[64][65];
    const int k0 = blockIdx.y * 64, n0 = blockIdx.x * 64, tid = threadIdx.x;
#pragma unroll
    for (int i = 0; i < 16; i++) {
        int idx = tid + i * 256;
        int kk = idx >> 6, nn = idx & 63;
        int n = n0 + nn;
        float v = (n < N) ? src[(size_t)(k0 + kk) * N + n] : 0.f;
        tile[kk][nn] = f2b(v);
    }
    __syncthreads();
#pragma unroll
    for (int i = 0; i < 16; i++) {
        int idx = tid + i * 256;
        int nn = idx >> 6, kk = idx & 63;
        int n = n0 + nn;
        if (n < Npad) dst[(size_t)n * ldK + koff + k0 + kk] = tile[kk][nn];
    }
}

// ---------------------------------------------------------------------------
// P1: feats f32 [n][c][p16] -> fT bf16 [n*16+p][1280]. grid (20 cch, 256 n).
__global__ __launch_bounds__(256) void ftrans_kernel(
    const float* __restrict__ feats, u16* __restrict__ fT)
{
    const int cch = blockIdx.x, n = blockIdx.y, tid = threadIdx.x;
    __shared__ u16 lt[64][17];
    const int c0 = cch * 64;
    const int c = tid >> 2, p4 = (tid & 3) * 4;
    float4 v = *(const float4*)(feats + (size_t)n * 20480 + (size_t)(c0 + c) * 16 + p4);
    lt[c][p4] = f2b(v.x); lt[c][p4 + 1] = f2b(v.y);
    lt[c][p4 + 2] = f2b(v.z); lt[c][p4 + 3] = f2b(v.w);
    __syncthreads();
    const int p = tid >> 4, cg = tid & 15;
    ushort4 o;
    o.x = lt[cg * 4 + 0][p]; o.y = lt[cg * 4 + 1][p];
    o.z = lt[cg * 4 + 2][p]; o.w = lt[cg * 4 + 3][p];
    *(ushort4*)(fT + (size_t)(n * 16 + p) * 1280 + c0 + cg * 4) = o;
}

// ---------------------------------------------------------------------------
// P2 (MFMA): Ab[row][col] = fT[row] @ WpT^T + bp, row = n*16+p.
// grid (4 ct, 64 rt) = 256 blocks; wave covers 64 rows x 32 cols.
__global__ __launch_bounds__(256) void proj_gemm_kernel(
    const u16* __restrict__ fT, const u16* __restrict__ WpT,
    const float* __restrict__ bp, u16* __restrict__ Ab)
{
    const int ct = blockIdx.x, rt = blockIdx.y;
    const int tid = threadIdx.x, w = tid >> 6, lane = tid & 63;
    const int r0 = rt * 64;
    const int lm = lane & 15, lkq = lane >> 4, lk = lkq * 8;
    const int nbase = ct * 128 + w * 32;

    f32x4 acc[4][2];
#pragma unroll
    for (int mt = 0; mt < 4; mt++)
#pragma unroll
        for (int nt = 0; nt < 2; nt++) acc[mt][nt] = (f32x4){0.f, 0.f, 0.f, 0.f};

    for (int kc = 0; kc < 1280; kc += 32) {
        bf16x8 af[4];
#pragma unroll
        for (int mt = 0; mt < 4; mt++)
            af[mt] = *(const bf16x8*)(fT + (size_t)(r0 + mt * 16 + lm) * 1280 + kc + lk);
#pragma unroll
        for (int nt = 0; nt < 2; nt++) {
            bf16x8 bfg = *(const bf16x8*)(WpT + (size_t)(nbase + nt * 16 + lm) * 1280 + kc + lk);
#pragma unroll
            for (int mt = 0; mt < 4; mt++)
                acc[mt][nt] = __builtin_amdgcn_mfma_f32_16x16x32_bf16(af[mt], bfg, acc[mt][nt], 0, 0, 0);
        }
    }
    float bbv[2];
#pragma unroll
    for (int nt = 0; nt < 2; nt++) bbv[nt] = bp[nbase + nt * 16 + lm];
#pragma unroll
    for (int mt = 0; mt < 4; mt++)
#pragma unroll
        for (int nt = 0; nt < 2; nt++)
#pragma unroll
            for (int r = 0; r < 4; r++) {
                int row = r0 + mt * 16 + lkq * 4 + r;
                int col = nbase + nt * 16 + lm;
                Ab[(size_t)row * 512 + col] = f2b(acc[mt][nt][r] + bbv[nt]);
            }
}

// ---------------------------------------------------------------------------
// P3: c0 = h0 = mean_p Ab (f32); hb0 = bf16(h0). grid 256.
__global__ __launch_bounds__(256) void projmean_kernel(
    const u16* __restrict__ Ab, float* __restrict__ c0, u16* __restrict__ hb0)
{
    const int n = blockIdx.x, tid = threadIdx.x;
    const int col0 = tid, col1 = tid + 256;
    float s0 = 0.f, s1 = 0.f;
#pragma unroll
    for (int p = 0; p < 16; p++) {
        const u16* ap = Ab + ((size_t)n * 16 + p) * 512;
        s0 += b2f(ap[col0]);
        s1 += b2f(ap[col1]);
    }
    s0 *= 0.0625f; s1 *= 0.0625f;
    c0[n * 512 + col0] = s0;  c0[n * 512 + col1] = s1;
    hb0[(size_t)n * 512 + col0] = f2b(s0);
    hb0[(size_t)n * 512 + col1] = f2b(s1);
}

// ---------------------------------------------------------------------------
// K2 (MFMA): xpb = embed@Wx + b  (bf16), rows stored as [t][n]
__global__ __launch_bounds__(256) void xp_mfma_kernel(
    const int* __restrict__ caps, const float* __restrict__ We,
    const u16* __restrict__ Wxt, const float* __restrict__ bb,
    u16* __restrict__ xpb)
{
    const int ct = blockIdx.x, rt = blockIdx.y;
    const int tid = threadIdx.x, w = tid >> 6, lane = tid & 63;
    const int r0 = rt * 64;
    const int lm = lane & 15, lkq = lane >> 4, lk = lkq * 8;
    const int nbase = ct * 512 + w * 128;

    int capm[4];
#pragma unroll
    for (int mt = 0; mt < 4; mt++) {
        int row = r0 + mt * 16 + lm;
        capm[mt] = caps[(row >> 5) * 33 + (row & 31)];
    }
    f32x4 acc[4][8];
#pragma unroll
    for (int mt = 0; mt < 4; mt++)
#pragma unroll
        for (int nt = 0; nt < 8; nt++) acc[mt][nt] = (f32x4){0.f, 0.f, 0.f, 0.f};

    for (int kc = 0; kc < 256; kc += 32) {
        bf16x8 af[4];
#pragma unroll
        for (int mt = 0; mt < 4; mt++) {
            const float* ap = We + (size_t)capm[mt] * 256 + kc + lk;
            float4 f0 = *(const float4*)ap;
            float4 f1 = *(const float4*)(ap + 4);
            bf16x8 t;
            t[0] = (short)f2b(f0.x); t[1] = (short)f2b(f0.y);
            t[2] = (short)f2b(f0.z); t[3] = (short)f2b(f0.w);
            t[4] = (short)f2b(f1.x); t[5] = (short)f2b(f1.y);
            t[6] = (short)f2b(f1.z); t[7] = (short)f2b(f1.w);
            af[mt] = t;
        }
#pragma unroll
        for (int nt = 0; nt < 8; nt++) {
            bf16x8 bfg = *(const bf16x8*)(Wxt + (size_t)(nbase + nt * 16 + lm) * 256 + kc + lk);
#pragma unroll
            for (int mt = 0; mt < 4; mt++)
                acc[mt][nt] = __builtin_amdgcn_mfma_f32_16x16x32_bf16(af[mt], bfg, acc[mt][nt], 0, 0, 0);
        }
    }
    float bbv[8];
#pragma unroll
    for (int nt = 0; nt < 8; nt++) bbv[nt] = bb[nbase + nt * 16 + lm];
#pragma unroll
    for (int mt = 0; mt < 4; mt++)
#pragma unroll
        for (int nt = 0; nt < 8; nt++)
#pragma unroll
            for (int r = 0; r < 4; r++) {
                int row = r0 + mt * 16 + lkq * 4 + r;   // row = n*32 + t
                int col = nbase + nt * 16 + lm;
                float v = acc[mt][nt][r] + bbv[nt];
                xpb[((size_t)(row & 31) * 256 + (row >> 5)) * 2048 + col] = f2b(v);
            }
}

// ---------------------------------------------------------------------------
// K3 (MFMA, once): preaw2[n][col][p] = (A[n,:,p] @ Wattn)[col]  (bf16 out)
// rows' = n*16+p == Ab's native row order. Stores are 512B-contiguous/wave.
__global__ __launch_bounds__(256) void preaw_mfma_kernel(
    const u16* __restrict__ Ab, const u16* __restrict__ what,
    u16* __restrict__ preaw)
{
    const int ct = blockIdx.x, rt = blockIdx.y;
    const int tid = threadIdx.x, w = tid >> 6, lane = tid & 63;
    const int r0 = rt * 64;
    const int lm = lane & 15, lkq = lane >> 4, lk = lkq * 8;
    const int nbase = ct * 512 + w * 128;

    f32x4 acc[4][8];
#pragma unroll
    for (int mt = 0; mt < 4; mt++)
#pragma unroll
        for (int nt = 0; nt < 8; nt++) acc[mt][nt] = (f32x4){0.f, 0.f, 0.f, 0.f};

    for (int kc = 0; kc < 512; kc += 32) {
        bf16x8 af[4];
#pragma unroll
        for (int mt = 0; mt < 4; mt++)
            af[mt] = *(const bf16x8*)(Ab + (size_t)(r0 + mt * 16 + lm) * 512 + kc + lk);
#pragma unroll
        for (int nt = 0; nt < 8; nt++) {
            bf16x8 bfg = *(const bf16x8*)(what + (size_t)(nbase + nt * 16 + lm) * 1024 + 512 + kc + lk);
#pragma unroll
            for (int mt = 0; mt < 4; mt++)
                acc[mt][nt] = __builtin_amdgcn_mfma_f32_16x16x32_bf16(af[mt], bfg, acc[mt][nt], 0, 0, 0);
        }
    }
#pragma unroll
    for (int mt = 0; mt < 4; mt++) {
        int nIdx = (r0 >> 4) + mt;                      // n for this 16-row group
#pragma unroll
        for (int nt = 0; nt < 8; nt++) {
            int col = nbase + nt * 16 + lm;
            ushort4 o;
            o.x = f2b(acc[mt][nt][0]); o.y = f2b(acc[mt][nt][1]);
            o.z = f2b(acc[mt][nt][2]); o.w = f2b(acc[mt][nt][3]);
            *(ushort4*)(preaw + (size_t)nIdx * 32768 + (size_t)col * 16 + lkq * 4) = o;
        }
    }
}

// ---------------------------------------------------------------------------
// K4 (once): scores for t=0: scp[0][n][p] = h0[n]·A[n,p]; zero cg>0
__global__ __launch_bounds__(64) void score_init_kernel(
    const u16* __restrict__ hb0, const u16* __restrict__ Ab,
    float* __restrict__ scp)
{
    const int n = blockIdx.x, lane = threadIdx.x;
    const u16* hp = hb0 + (size_t)n * 512 + lane * 8;
    ushort4 h0 = *(const ushort4*)hp, h1 = *(const ushort4*)(hp + 4);
    float hv0 = b2f(h0.x), hv1 = b2f(h0.y), hv2 = b2f(h0.z), hv3 = b2f(h0.w);
    float hv4 = b2f(h1.x), hv5 = b2f(h1.y), hv6 = b2f(h1.z), hv7 = b2f(h1.w);
    float mine = 0.f;
#pragma unroll
    for (int p = 0; p < 16; p++) {
        const u16* ap = Ab + (size_t)n * 8192 + p * 512 + lane * 8;
        ushort4 a0 = *(const ushort4*)ap, a1 = *(const ushort4*)(ap + 4);
        float s = hv0*b2f(a0.x) + hv1*b2f(a0.y) + hv2*b2f(a0.z) + hv3*b2f(a0.w)
                + hv4*b2f(a1.x) + hv5*b2f(a1.y) + hv6*b2f(a1.z) + hv7*b2f(a1.w);
#pragma unroll
        for (int mask = 1; mask <= 32; mask <<= 1) s += __shfl_xor(s, mask, 64);
        if (lane == p) mine = s;
    }
    if (lane < 16) scp[n * 16 + lane] = mine;
    for (int i = lane; i < 31 * 16; i += 64)
        scp[(1 + (i >> 4)) * 4096 + n * 16 + (i & 15)] = 0.f;
}

// ---------------------------------------------------------------------------
// K5 v3 (per step): ILP-first rewrite. All latency-bound loads (what B-frags,
// preaw [n][col][p] slices, xpt, c, score-phase Ab) prefetched at entry.
// MFMA loop overlaps softmax; gates computed by ALL 4 waves (1 row each).
// grid (16 rt, 32 cg), 4 waves, <=2 waves/EU keeps VGPR cap at 256.
__global__ __launch_bounds__(256, 2) void gates_fused_kernel(
    const u16* __restrict__ hb_in, const float* __restrict__ scp_in,
    const u16* __restrict__ what, const u16* __restrict__ preaw,
    const u16* __restrict__ xpt, const u16* __restrict__ Ab,
    float* __restrict__ c, u16* __restrict__ hb_out,
    u16* __restrict__ hallbt, float* __restrict__ scp_out)
{
    const int rt = blockIdx.x, cg = blockIdx.y;
    const int tid = threadIdx.x, ty = tid >> 6, lane = tid & 63;
    const int lm = lane & 15, lkq = lane >> 4, lk = lkq * 8;
    const int r0 = rt * 16, hc0 = cg * 16;

    __shared__ u16 hs[16 * 520];
    __shared__ float sred[16][17];
    __shared__ float wts[16][17];
    __shared__ float gred[4][16][18];
    __shared__ u16 hnew[16][16];

    const int col = ty * 512 + hc0 + lm;

    // ---- prefetch: B fragments of `what` (K=512 -> 16 x 16B) ----
    const u16* brow = what + (size_t)col * 1024 + lk;
    bf16x8 bfa[16];
#pragma unroll
    for (int i = 0; i < 16; i++) bfa[i] = *(const bf16x8*)(brow + i * 32);

    // ---- prefetch: preaw slices [n][col][p16] = 32B per r ----
    ushort4 pwv[4][4];
#pragma unroll
    for (int r = 0; r < 4; r++) {
        const u16* pp = preaw + (size_t)(r0 + lkq * 4 + r) * 32768 + (size_t)col * 16;
#pragma unroll
        for (int j = 0; j < 4; j++) pwv[r][j] = *(const ushort4*)(pp + j * 4);
    }
    // ---- prefetch: xp bias terms ----
    u16 xpw[4];
#pragma unroll
    for (int r = 0; r < 4; r++) xpw[r] = xpt[(size_t)(r0 + lkq * 4 + r) * 2048 + col];

    // ---- prefetch: cell state for this thread's gate row ----
    const int rg = lkq * 4 + ty;
    const int idxg = (r0 + rg) * 512 + hc0 + lm;
    float cin = c[idxg];

    // ---- prefetch: Ab row slice for score phase (32B) ----
    const int rs = tid >> 4, ps = tid & 15;
    ushort4 abv[4];
    {
        const u16* ap = Ab + (size_t)(r0 + rs) * 8192 + ps * 512 + hc0;
#pragma unroll
        for (int j = 0; j < 4; j++) abv[j] = *(const ushort4*)(ap + j * 4);
    }

    // ---- stage h into LDS + reduce score partials ----
#pragma unroll
    for (int i = 0; i < 8; i++) {
        int fid = tid + i * 256;
        int rr = fid >> 7, c4 = fid & 127;
        *(ushort4*)&hs[rr * 520 + c4 * 4] =
            *(const ushort4*)(hb_in + (size_t)(r0 + rr) * 512 + c4 * 4);
    }
    {
        float s = 0.f;
#pragma unroll
        for (int g = 0; g < 32; g++) s += scp_in[g * 4096 + (r0 + rs) * 16 + ps];
        sred[rs][ps] = s * 0.04419417382415922f;
    }
    __syncthreads();                                   // B1
    {
        float m = -1e30f;
#pragma unroll
        for (int q = 0; q < 16; q++) m = fmaxf(m, sred[rs][q]);
        float su = 0.f;
#pragma unroll
        for (int q = 0; q < 16; q++) su += __expf(sred[rs][q] - m);
        wts[rs][ps] = __expf(sred[rs][ps] - m) / su;
    }
    // ---- MFMA: h @ Wh (B prefetched; sits between wts write and B2) ----
    f32x4 acc = (f32x4){0.f, 0.f, 0.f, 0.f};
    const u16* arow = &hs[lm * 520 + lk];
#pragma unroll
    for (int i = 0; i < 16; i++) {
        bf16x8 af = *(const bf16x8*)(arow + i * 32);
        acc = __builtin_amdgcn_mfma_f32_16x16x32_bf16(af, bfa[i], acc, 0, 0, 0);
    }
    __syncthreads();                                   // B2 (wts visible)
#pragma unroll
    for (int r = 0; r < 4; r++) {
        const int rl = lkq * 4 + r;
        float s = acc[r] + b2f(xpw[r]);
#pragma unroll
        for (int j = 0; j < 4; j++) {
            s += wts[rl][j * 4 + 0] * b2f(pwv[r][j].x);
            s += wts[rl][j * 4 + 1] * b2f(pwv[r][j].y);
            s += wts[rl][j * 4 + 2] * b2f(pwv[r][j].z);
            s += wts[rl][j * 4 + 3] * b2f(pwv[r][j].w);
        }
        gred[ty][rl][lm] = s;
    }
    __syncthreads();                                   // B3
    {
        float ai  = gred[0][rg][lm];
        float af_ = gred[1][rg][lm];
        float ao  = gred[2][rg][lm];
        float ag  = gred[3][rg][lm];
        float ig = 1.f / (1.f + __expf(-ai));
        float fg = 1.f / (1.f + __expf(-af_));
        float og = 1.f / (1.f + __expf(-ao));
        float gv = tanhf(ag);
        float cn = fg * cin + ig * gv;
        float hn = og * tanhf(cn);
        c[idxg] = cn;
        u16 hbv = f2b(hn);
        hb_out[idxg] = hbv;
        hallbt[idxg] = hbv;
        hnew[rg][lm] = hbv;
    }
    __syncthreads();                                   // B4
    {
        float s = 0.f;
#pragma unroll
        for (int j = 0; j < 4; j++) {
            s += b2f(hnew[rs][j * 4 + 0]) * b2f(abv[j].x);
            s += b2f(hnew[rs][j * 4 + 1]) * b2f(abv[j].y);
            s += b2f(hnew[rs][j * 4 + 2]) * b2f(abv[j].z);
            s += b2f(hnew[rs][j * 4 + 3]) * b2f(abv[j].w);
        }
        scp_out[cg * 4096 + (r0 + rs) * 16 + ps] = s;
    }
}

// ---------------------------------------------------------------------------
// K6 (MFMA v5): vocab + fused logsumexp. 2-phase double-buffered pipeline:
// counted s_waitcnt vmcnt(3) + raw barriers; both-sides LDS swizzle.
// grid (40 ct, 64 rt); 512 thr = 8 waves (2x4); tile 128x256, BK=32.
__global__ __launch_bounds__(512) void vocab_mfma_kernel(
    const u16* __restrict__ hallb, const u16* __restrict__ Wvt,
    const float* __restrict__ bv, const int* __restrict__ caps,
    float* __restrict__ pmax, float* __restrict__ psum, float* __restrict__ tgt)
{
    const int ct = blockIdx.x, rt = blockIdx.y;
    const int tid = threadIdx.x, w = tid >> 6, lane = tid & 63;
    const int wr = w >> 2, wc = w & 3;                // 2 x 4 wave grid
    const int r0 = rt * 128, c0 = ct * 256;
    const int lm = lane & 15, lkq = lane >> 4;
    const int swz = lkq ^ ((lm >> 1) & 3);            // read-side XOR

    __shared__ u16 As[2][512 * 8];                    // 2 x 8 KB, 16B units
    __shared__ u16 Bs[2][1024 * 8];                   // 2 x 16 KB
    __shared__ int tvs[128];
    __shared__ float cm[128][4], cs[128][4];

    if (tid < 128) {
        int row = r0 + tid;                           // row = t*256 + n
        tvs[tid] = caps[(row & 255) * 33 + (row >> 8) + 1];
    }

    f32x4 acc[4][4];
#pragma unroll
    for (int mt = 0; mt < 4; mt++)
#pragma unroll
        for (int nt = 0; nt < 4; nt++) acc[mt][nt] = (f32x4){0.f, 0.f, 0.f, 0.f};

    const int sA = w * 64 + lane;                     // 0..511
    const int rA = sA >> 2, kA = (sA & 3) ^ ((rA >> 1) & 3);
    const u16* gA = hallb + (size_t)(r0 + rA) * 512 + kA * 8;
    const int sB0 = w * 64 + lane, sB1 = sB0 + 512;   // 0..1023
    const int cB0 = sB0 >> 2, kB0 = (sB0 & 3) ^ ((cB0 >> 1) & 3);
    const int cB1 = sB1 >> 2, kB1 = (sB1 & 3) ^ ((cB1 >> 1) & 3);
    const u16* gB0 = Wvt + (size_t)(c0 + cB0) * 512 + kB0 * 8;
    const u16* gB1 = Wvt + (size_t)(c0 + cB1) * 512 + kB1 * 8;

    auto stage = [&](int buf, int kc) {
        gload16(gA + kc, &As[buf][w * 512]);
        gload16(gB0 + kc, &Bs[buf][w * 512]);
        gload16(gB1 + kc, &Bs[buf][(w + 8) * 512]);
    };
    auto compute = [&](int buf) {
        bf16x8 af[4], bfr[4];
#pragma unroll
        for (int mt = 0; mt < 4; mt++)
            af[mt] = *(const bf16x8*)&As[buf][((wr * 64 + mt * 16 + lm) * 4 + swz) * 8];
#pragma unroll
        for (int nt = 0; nt < 4; nt++)
            bfr[nt] = *(const bf16x8*)&Bs[buf][((wc * 64 + nt * 16 + lm) * 4 + swz) * 8];
#pragma unroll
        for (int nt = 0; nt < 4; nt++)
#pragma unroll
            for (int mt = 0; mt < 4; mt++)
                acc[mt][nt] = __builtin_amdgcn_mfma_f32_16x16x32_bf16(af[mt], bfr[nt], acc[mt][nt], 0, 0, 0);
    };

    stage(0, 0);
#pragma unroll 1
    for (int t = 0; t < 15; ++t) {
        const int cur = t & 1;
        stage(cur ^ 1, (t + 1) * 32);                 // prefetch next K-tile
        asm volatile("s_waitcnt vmcnt(3)" ::: "memory");  // own current-buf loads done
        __builtin_amdgcn_s_barrier();                 // all waves' writes visible
        compute(cur);
        __builtin_amdgcn_s_barrier();                 // reads done before overwrite
    }
    asm volatile("s_waitcnt vmcnt(0)" ::: "memory");
    __builtin_amdgcn_s_barrier();
    compute(1);                                       // t=15 -> buf 1

    float bvv[4]; bool vld[4];
#pragma unroll
    for (int nt = 0; nt < 4; nt++) {
        int col = c0 + wc * 64 + nt * 16 + lm;
        vld[nt] = (col < NV);
        bvv[nt] = vld[nt] ? bv[col] : 0.f;
    }
#pragma unroll
    for (int mt = 0; mt < 4; mt++)
#pragma unroll
        for (int r = 0; r < 4; r++) {
            int rloc = wr * 64 + mt * 16 + lkq * 4 + r;
            int row = r0 + rloc;
            int tv = tvs[rloc];
            float vals[4]; float m = -1e30f;
#pragma unroll
            for (int nt = 0; nt < 4; nt++) {
                int col = c0 + wc * 64 + nt * 16 + lm;
                float v = vld[nt] ? (acc[mt][nt][r] + bvv[nt]) : -1e30f;
                vals[nt] = v;
                m = fmaxf(m, v);
                if (col == tv) tgt[row] = v;
            }
#pragma unroll
            for (int mask = 1; mask <= 8; mask <<= 1) m = fmaxf(m, __shfl_xor(m, mask, 64));
            float s = 0.f;
#pragma unroll
            for (int nt = 0; nt < 4; nt++) s += __expf(vals[nt] - m);
#pragma unroll
            for (int mask = 1; mask <= 8; mask <<= 1) s += __shfl_xor(s, mask, 64);
            if (lm == 0) { cm[rloc][wc] = m; cs[rloc][wc] = s; }
        }
    __syncthreads();
    if (tid < 128) {
        float M = -1e30f;
#pragma unroll
        for (int q = 0; q < 4; q++) M = fmaxf(M, cm[tid][q]);
        float S = 0.f;
#pragma unroll
        for (int q = 0; q < 4; q++) S += cs[tid][q] * __expf(cm[tid][q] - M);
        int row = r0 + tid;
        pmax[row * VT_N + ct] = M;
        psum[row * VT_N + ct] = S;
    }
}

// ---------------------------------------------------------------------------
__global__ __launch_bounds__(256) void loss_reduce_kernel(
    const float* __restrict__ pmax, const float* __restrict__ psum,
    const float* __restrict__ tgt, const int* __restrict__ caps,
    float* __restrict__ loss)
{
    const int row = blockIdx.x * 256 + threadIdx.x;
    float nll = 0.f;
    const int t = row >> 8, n = row & 255;
    const int tv = caps[n * 33 + t + 1];
    if (tv != 0) {
        float M = -1e30f;
#pragma unroll
        for (int vt = 0; vt < VT_N; vt++) M = fmaxf(M, pmax[row * VT_N + vt]);
        float S = 0.f;
#pragma unroll
        for (int vt = 0; vt < VT_N; vt++) S += psum[row * VT_N + vt] * __expf(pmax[row * VT_N + vt] - M);
        nll = logf(S) + M - tgt[row];
    }
#pragma unroll
    for (int off = 32; off; off >>= 1) nll += __shfl_down(nll, off, 64);
    __shared__ float r4[4];
    if ((threadIdx.x & 63) == 0) r4[threadIdx.x >> 6] = nll;
    __syncthreads();
    if (threadIdx.x == 0)
        atomicAdd(loss, (r4[0] + r4[1] + r4[2] + r4[3]) * (1.f / 256.f));
}

__global__ void finalize_kernel(const float* __restrict__ loss, float* __restrict__ out)
{
    if (threadIdx.x == 0 && blockIdx.x == 0) out[0] = loss[0];
}

// ---------------------------------------------------------------------------
extern "C" void kernel_launch(void* const* d_in, const int* in_sizes, int n_in,
                              void* d_out, int out_size, void* d_ws, size_t ws_size,
                              hipStream_t stream) {
    const float* feats = (const float*)d_in[0];
    const int*   caps  = (const int*)d_in[1];
    const float* Wp    = (const float*)d_in[2];
    const float* bp    = (const float*)d_in[3];
    const float* We    = (const float*)d_in[4];
    const float* Wx    = (const float*)d_in[5];
    const float* Wh    = (const float*)d_in[6];
    const float* Wattn = (const float*)d_in[7];
    const float* bb    = (const float*)d_in[8];
    const float* Wv    = (const float*)d_in[9];
    const float* bv    = (const float*)d_in[10];

    char* ws = (char*)d_ws;
    float* c     = (float*)(ws + B_C);
    float* scp0  = (float*)(ws + B_SCP);
    float* scp1  = scp0 + (size_t)32 * 4096;
    float* pmax  = (float*)(ws + B_PMAX);
    float* psum  = (float*)(ws + B_PSUM);
    float* tgt   = (float*)(ws + B_TGT);
    float* loss  = (float*)(ws + B_LOSS);
    u16*   Ab    = (u16*)(ws + B_AB);
    u16*   xpb   = (u16*)(ws + B_XPB);
    u16*   hallb = (u16*)(ws + B_HALLB);
    u16*   wvt   = (u16*)(ws + B_WVT);
    u16*   wxt   = (u16*)(ws + B_WXT);
    u16*   what  = (u16*)(ws + B_WHAT);
    u16*   hb[2] = { (u16*)(ws + B_HB0), (u16*)(ws + B_HB1) };
    u16*   preaw = (u16*)(ws + B_PREAW);
    u16*   fT    = wvt;      // alias: dead before tconv(Wv) overwrites
    u16*   WpT   = xpb;      // alias: dead before xp_mfma overwrites

    hipMemsetAsync(loss, 0, sizeof(float), stream);

    // --- proj path (MFMA): feats^T -> GEMM -> Ab, mean -> c0/hb0 ---
    ftrans_kernel<<<dim3(20, 256), 256, 0, stream>>>(feats, fT);
    tconv_kernel<<<dim3(8, 20), 256, 0, stream>>>(Wp, WpT, 1280, 512, 512, 1280, 0);
    proj_gemm_kernel<<<dim3(4, 64), 256, 0, stream>>>(fT, WpT, bp, Ab);
    projmean_kernel<<<256, 256, 0, stream>>>(Ab, c, hb[0]);

    // --- weight preps (overwrite fT / WpT aliases) ---
    tconv_kernel<<<dim3(160, 8), 256, 0, stream>>>(Wv, wvt, 512, NV, NVP, 512, 0);
    tconv_kernel<<<dim3(32, 4),  256, 0, stream>>>(Wx, wxt, 256, 2048, 2048, 256, 0);
    tconv_kernel<<<dim3(32, 8),  256, 0, stream>>>(Wh, what, 512, 2048, 2048, 1024, 0);
    tconv_kernel<<<dim3(32, 8),  256, 0, stream>>>(Wattn, what, 512, 2048, 2048, 1024, 512);
    xp_mfma_kernel<<<dim3(4, 128), 256, 0, stream>>>(caps, We, wxt, bb, xpb);
    preaw_mfma_kernel<<<dim3(4, 64), 256, 0, stream>>>(Ab, what, preaw);
    score_init_kernel<<<256, 64, 0, stream>>>(hb[0], Ab, scp0);

    for (int t = 0; t < NT; t++) {
        const int in = t & 1;
        gates_fused_kernel<<<dim3(16, 32), 256, 0, stream>>>(
            hb[in], in ? scp1 : scp0, what, preaw,
            xpb + (size_t)t * 524288, Ab, c,
            hb[1 - in], hallb + (size_t)t * 131072,
            in ? scp0 : scp1);
    }

    vocab_mfma_kernel<<<dim3(VT_N, 64), 512, 0, stream>>>(
        hallb, wvt, bv, caps, pmax, psum, tgt);
    loss_reduce_kernel<<<32, 256, 0, stream>>>(pmax, psum, tgt, caps, loss);
    finalize_kernel<<<1, 64, 0, stream>>>(loss, (float*)d_out);
}